// Round 1
// baseline (962.976 us; speedup 1.0000x reference)
//
#include <hip/hip_runtime.h>
#include <math.h>

// ---------------- problem constants ----------------
constexpr int cB = 256, cN = 256, cF = 128, cO = 256;
constexpr int BN = cB * cN;                 // 65536 rows
constexpr float D2_FLOOR = 1e-12f;
constexpr float EPS_F = 1.401298464324817e-45f;  // np.spacing(float32(0))

// ---------------- workspace layout (floats) ----------------
// xw buffer is dead after k_gram/k_sq -> reused for x2.
constexpr size_t OFF_XW = 0;                              // xw  [BN,128]  (later x2)
constexpr size_t OFF_X0 = OFF_XW + (size_t)BN * cF;       // x0m [BN,128]
constexpr size_t OFF_X1 = OFF_X0 + (size_t)BN * cF;       // x1  [BN,128]
constexpr size_t OFF_X3 = OFF_X1 + (size_t)BN * cF;       // x3  [BN,128]
constexpr size_t OFF_L  = OFF_X3 + (size_t)BN * cF;       // W then L in place [B,N,N]
constexpr size_t OFF_SQ = OFF_L + (size_t)BN * cN;        // sq  [BN]
constexpr size_t OFF_DI = OFF_SQ + (size_t)BN;            // dinv[BN]
// total = OFF_DI + BN = 50,528,256 floats ~ 193 MiB

// Stage a 64x64 fp32 tile (row stride ld) into LDS laid out [64][65].
__device__ __forceinline__ void stage64(const float* __restrict__ src, int ld,
                                        float* __restrict__ dst) {
  int t = threadIdx.x;
#pragma unroll
  for (int it = 0; it < 4; ++it) {
    int idx = it * 1024 + t * 4;
    int r = idx >> 6, c = idx & 63;
    const float4 v = *(const float4*)(src + (size_t)r * ld + c);
    float* d = dst + r * 65 + c;
    d[0] = v.x; d[1] = v.y; d[2] = v.z; d[3] = v.w;
  }
}

// ---------------- kernel 1: x0m = x * mask ----------------
__global__ __launch_bounds__(256) void k_mask(const float* __restrict__ x,
                                              const int* __restrict__ na_p,
                                              float* __restrict__ x0) {
  size_t e = ((size_t)blockIdx.x * 256 + threadIdx.x) * 4;
  int n = (int)((e >> 7) & 255);
  int b = (int)(e >> 15);
  float m = (n < na_p[b]) ? 1.f : 0.f;
  float4 v = *(const float4*)(x + e);
  v.x *= m; v.y *= m; v.z *= m; v.w *= m;
  *(float4*)(x0 + e) = v;
}

// ---------------- kernel 2: xw = x0m @ M_L ----------------
__global__ __launch_bounds__(256) void k_xw(const float* __restrict__ x0,
                                            const float* __restrict__ M,
                                            float* __restrict__ xw) {
  int r0 = blockIdx.y * 64;  // row tile in [0,BN)
  int c0 = blockIdx.x * 64;  // col tile in F
  __shared__ float At[64 * 65];
  __shared__ float Bt[64 * 65];
  int tx = threadIdx.x & 15, ty = threadIdx.x >> 4;
  float acc[4][4] = {};
  for (int kc = 0; kc < 2; ++kc) {
    int k0 = kc * 64;
    __syncthreads();
    stage64(x0 + (size_t)r0 * cF + k0, cF, At);       // At[r][kk] = x0[r0+r, k0+kk]
    stage64(M + (size_t)k0 * cF + c0, cF, Bt);        // Bt[kk][c] = M[k0+kk, c0+c]
    __syncthreads();
#pragma unroll 4
    for (int kk = 0; kk < 64; ++kk) {
      float av[4], bv[4];
#pragma unroll
      for (int a = 0; a < 4; ++a) av[a] = At[(ty * 4 + a) * 65 + kk];
#pragma unroll
      for (int b2 = 0; b2 < 4; ++b2) bv[b2] = Bt[kk * 65 + tx * 4 + b2];
#pragma unroll
      for (int a = 0; a < 4; ++a)
#pragma unroll
        for (int b2 = 0; b2 < 4; ++b2) acc[a][b2] = fmaf(av[a], bv[b2], acc[a][b2]);
    }
  }
#pragma unroll
  for (int a = 0; a < 4; ++a) {
    int row = r0 + ty * 4 + a;
    float4 r = {acc[a][0], acc[a][1], acc[a][2], acc[a][3]};
    *(float4*)(xw + (size_t)row * cF + c0 + tx * 4) = r;
  }
}

// ---------------- kernel 3: sq[bn] = sum_f xw^2 ----------------
__global__ __launch_bounds__(128) void k_sq(const float* __restrict__ xw,
                                            float* __restrict__ sq) {
  int bn = blockIdx.x;
  int t = threadIdx.x;
  float v = xw[(size_t)bn * cF + t];
  float s = v * v;
#pragma unroll
  for (int o = 32; o > 0; o >>= 1) s += __shfl_down(s, o);
  __shared__ float r2[2];
  if ((t & 63) == 0) r2[t >> 6] = s;
  __syncthreads();
  if (t == 0) sq[bn] = r2[0] + r2[1];
}

// ---------------- kernel 4: W[b,i,j] = exp(-dist) * off ----------------
__global__ __launch_bounds__(256) void k_gram(const float* __restrict__ xw,
                                              const float* __restrict__ sq,
                                              const int* __restrict__ na_p,
                                              float* __restrict__ Wb) {
  int b = blockIdx.z, i0 = blockIdx.y * 64, j0 = blockIdx.x * 64;
  __shared__ float At[64 * 65];
  __shared__ float Bt[64 * 65];
  const float* base = xw + (size_t)b * cN * cF;
  int tx = threadIdx.x & 15, ty = threadIdx.x >> 4;
  float acc[4][4] = {};
  for (int kc = 0; kc < 2; ++kc) {
    int k0 = kc * 64;
    __syncthreads();
    stage64(base + (size_t)i0 * cF + k0, cF, At);
    stage64(base + (size_t)j0 * cF + k0, cF, Bt);
    __syncthreads();
#pragma unroll 4
    for (int kk = 0; kk < 64; ++kk) {
      float av[4], bv[4];
#pragma unroll
      for (int a = 0; a < 4; ++a) av[a] = At[(ty * 4 + a) * 65 + kk];
#pragma unroll
      for (int b2 = 0; b2 < 4; ++b2) bv[b2] = Bt[(tx * 4 + b2) * 65 + kk];
#pragma unroll
      for (int a = 0; a < 4; ++a)
#pragma unroll
        for (int b2 = 0; b2 < 4; ++b2) acc[a][b2] = fmaf(av[a], bv[b2], acc[a][b2]);
    }
  }
  int na = na_p[b];
  const float* sqb = sq + (size_t)b * cN;
  float* Wrow = Wb + ((size_t)b * cN + i0) * cN + j0;
#pragma unroll
  for (int a = 0; a < 4; ++a) {
    int i = i0 + ty * 4 + a;
    bool mi = i < na;
    float sqi = sqb[i];
    float4 r;
#pragma unroll
    for (int b2 = 0; b2 < 4; ++b2) {
      int j = j0 + tx * 4 + b2;
      float w = 0.f;
      if (mi && (j < na) && (i != j)) {
        float d2 = fmaxf(sqi + sqb[j] - 2.f * acc[a][b2], D2_FLOOR);
        w = expf(-sqrtf(d2));
      }
      (&r.x)[b2] = w;
    }
    *(float4*)(Wrow + (size_t)(ty * 4 + a) * cN + tx * 4) = r;
  }
}

// ---------------- kernel 5: deg -> dinv ----------------
__global__ __launch_bounds__(256) void k_dinv(const float* __restrict__ Wb,
                                              const int* __restrict__ na_p,
                                              float* __restrict__ dinv) {
  int bn = blockIdx.x;
  int b = bn >> 8, n = bn & 255;
  int t = threadIdx.x;
  float s = Wb[(size_t)bn * cN + t];
#pragma unroll
  for (int o = 32; o > 0; o >>= 1) s += __shfl_down(s, o);
  __shared__ float r4[4];
  if ((t & 63) == 0) r4[t >> 6] = s;
  __syncthreads();
  if (t == 0) {
    float deg = r4[0] + r4[1] + r4[2] + r4[3] + EPS_F;
    dinv[bn] = (n < na_p[b]) ? 1.f / sqrtf(deg) : 0.f;
  }
}

// ---------------- kernel 6: L_learn (to out) + L (in place over W) ----------------
__global__ __launch_bounds__(256) void k_L(const float* __restrict__ lap,
                                           const int* __restrict__ na_p,
                                           const float* __restrict__ dinv,
                                           float* __restrict__ LW,
                                           float* __restrict__ llearn) {
  size_t e = ((size_t)blockIdx.x * 256 + threadIdx.x) * 4;
  int j = (int)(e & 255);
  int i = (int)((e >> 8) & 255);
  int b = (int)(e >> 16);
  float4 w = *(const float4*)(LW + e);
  float4 lp = *(const float4*)(lap + e);
  float di = dinv[(size_t)b * cN + i];
  const float* djp = dinv + (size_t)b * cN + j;
  int na = na_p[b];
  float mi = (i < na) ? 1.f : 0.f;
  float4 ll, lo;
#pragma unroll
  for (int c = 0; c < 4; ++c) {
    float v = -di * (&w.x)[c] * djp[c];
    if (i == j + c && i < na) v += 1.f;
    (&ll.x)[c] = v;
    float mj = (j + c < na) ? 1.f : 0.f;
    (&lo.x)[c] = v + (&lp.x)[c] * mi * mj;
  }
  *(float4*)(llearn + e) = ll;
  *(float4*)(LW + e) = lo;
}

// ---------------- kernel 7: Chebyshev step Xo = alpha*(L@Xp) + beta*Xpp ----------------
__global__ __launch_bounds__(256) void k_cheb(const float* __restrict__ Lm,
                                              const float* __restrict__ Xp,
                                              const float* __restrict__ Xpp,
                                              float alpha, float beta,
                                              float* __restrict__ Xo) {
  int b = blockIdx.z, i0 = blockIdx.y * 64, f0 = blockIdx.x * 64;
  __shared__ float At[64 * 65];
  __shared__ float Bt[64 * 65];
  const float* Lb = Lm + (size_t)b * cN * cN;
  const float* Xb = Xp + (size_t)b * cN * cF;
  int tx = threadIdx.x & 15, ty = threadIdx.x >> 4;
  float acc[4][4] = {};
  for (int kc = 0; kc < 4; ++kc) {
    int k0 = kc * 64;
    __syncthreads();
    stage64(Lb + (size_t)i0 * cN + k0, cN, At);       // At[r][kk] = L[i0+r, k0+kk]
    stage64(Xb + (size_t)k0 * cF + f0, cF, Bt);       // Bt[kk][c] = Xp[k0+kk, f0+c]
    __syncthreads();
#pragma unroll 4
    for (int kk = 0; kk < 64; ++kk) {
      float av[4], bv[4];
#pragma unroll
      for (int a = 0; a < 4; ++a) av[a] = At[(ty * 4 + a) * 65 + kk];
#pragma unroll
      for (int b2 = 0; b2 < 4; ++b2) bv[b2] = Bt[kk * 65 + tx * 4 + b2];
#pragma unroll
      for (int a = 0; a < 4; ++a)
#pragma unroll
        for (int b2 = 0; b2 < 4; ++b2) acc[a][b2] = fmaf(av[a], bv[b2], acc[a][b2]);
    }
  }
#pragma unroll
  for (int a = 0; a < 4; ++a) {
    int row = i0 + ty * 4 + a;
    size_t o = (size_t)b * cN * cF + (size_t)row * cF + f0 + tx * 4;
    float4 r;
    if (beta != 0.f) {
      const float4 p = *(const float4*)(Xpp + o);
#pragma unroll
      for (int b2 = 0; b2 < 4; ++b2) (&r.x)[b2] = alpha * acc[a][b2] + beta * (&p.x)[b2];
    } else {
#pragma unroll
      for (int b2 = 0; b2 < 4; ++b2) (&r.x)[b2] = alpha * acc[a][b2];
    }
    *(float4*)(Xo + o) = r;
  }
}

// ---------------- kernel 8: out = relu((xc@weight + bias) * mask) ----------------
__global__ __launch_bounds__(256) void k_out(const float* __restrict__ x0,
                                             const float* __restrict__ x1,
                                             const float* __restrict__ x2,
                                             const float* __restrict__ x3,
                                             const float* __restrict__ wgt,
                                             const float* __restrict__ bias,
                                             const int* __restrict__ na_p,
                                             float* __restrict__ out) {
  int r0 = blockIdx.y * 64, o0 = blockIdx.x * 64;
  __shared__ float At[64 * 65];
  __shared__ float Bt[64 * 65];
  int tx = threadIdx.x & 15, ty = threadIdx.x >> 4;
  float acc[4][4] = {};
  const float* xs[4] = {x0, x1, x2, x3};
  for (int k = 0; k < 4; ++k) {
    const float* xk = xs[k];
    for (int fc = 0; fc < 2; ++fc) {
      __syncthreads();
      stage64(xk + (size_t)r0 * cF + fc * 64, cF, At);
      // weight row for LDS row kk is global row (fc*64+kk)*4 + k, stride 4*cO
      stage64(wgt + ((size_t)fc * 256 + k) * cO + o0, cO * 4, Bt);
      __syncthreads();
#pragma unroll 4
      for (int kk = 0; kk < 64; ++kk) {
        float av[4], bv[4];
#pragma unroll
        for (int a = 0; a < 4; ++a) av[a] = At[(ty * 4 + a) * 65 + kk];
#pragma unroll
        for (int b2 = 0; b2 < 4; ++b2) bv[b2] = Bt[kk * 65 + tx * 4 + b2];
#pragma unroll
        for (int a = 0; a < 4; ++a)
#pragma unroll
          for (int b2 = 0; b2 < 4; ++b2) acc[a][b2] = fmaf(av[a], bv[b2], acc[a][b2]);
      }
    }
  }
#pragma unroll
  for (int a = 0; a < 4; ++a) {
    int row = r0 + ty * 4 + a;
    int b = row >> 8, n = row & 255;
    float m = (n < na_p[b]) ? 1.f : 0.f;
    float4 r;
#pragma unroll
    for (int b2 = 0; b2 < 4; ++b2) {
      int o = o0 + tx * 4 + b2;
      float v = (acc[a][b2] + bias[o]) * m;
      (&r.x)[b2] = fmaxf(v, 0.f);
    }
    *(float4*)(out + (size_t)row * cO + o0 + tx * 4) = r;
  }
}

// ---------------- launcher ----------------
extern "C" void kernel_launch(void* const* d_in, const int* in_sizes, int n_in,
                              void* d_out, int out_size, void* d_ws, size_t ws_size,
                              hipStream_t stream) {
  const float* x    = (const float*)d_in[0];
  const float* lap  = (const float*)d_in[1];
  const int*   na   = (const int*)d_in[2];
  const float* M_L  = (const float*)d_in[3];
  const float* wgt  = (const float*)d_in[4];
  const float* bias = (const float*)d_in[5];

  float* out    = (float*)d_out;
  float* llearn = out + (size_t)BN * cO;   // second output, concatenated

  float* ws   = (float*)d_ws;
  float* xw   = ws + OFF_XW;
  float* x0m  = ws + OFF_X0;
  float* x1v  = ws + OFF_X1;
  float* x2v  = ws + OFF_XW;   // alias: xw is dead after k_gram/k_sq
  float* x3v  = ws + OFF_X3;
  float* Lbuf = ws + OFF_L;
  float* sqb  = ws + OFF_SQ;
  float* dnv  = ws + OFF_DI;

  k_mask<<<dim3(8192), 256, 0, stream>>>(x, na, x0m);
  k_xw<<<dim3(2, 1024), 256, 0, stream>>>(x0m, M_L, xw);
  k_sq<<<dim3(BN), 128, 0, stream>>>(xw, sqb);
  k_gram<<<dim3(4, 4, cB), 256, 0, stream>>>(xw, sqb, na, Lbuf);
  k_dinv<<<dim3(BN), 256, 0, stream>>>(Lbuf, na, dnv);
  k_L<<<dim3(16384), 256, 0, stream>>>(lap, na, dnv, Lbuf, llearn);
  k_cheb<<<dim3(2, 4, cB), 256, 0, stream>>>(Lbuf, x0m, x0m, 1.f, 0.f, x1v);
  k_cheb<<<dim3(2, 4, cB), 256, 0, stream>>>(Lbuf, x1v, x0m, 2.f, -1.f, x2v);
  k_cheb<<<dim3(2, 4, cB), 256, 0, stream>>>(Lbuf, x2v, x1v, 2.f, -1.f, x3v);
  k_out<<<dim3(4, 1024), 256, 0, stream>>>(x0m, x1v, x2v, x3v, wgt, bias, na, out);
}

// Round 2
// 427.643 us; speedup vs baseline: 2.2518x; 2.2518x over previous
//
#include <hip/hip_runtime.h>
#include <math.h>

typedef __bf16 bf16;
typedef __bf16 bf16x8 __attribute__((ext_vector_type(8)));
typedef __bf16 bf16x4 __attribute__((ext_vector_type(4)));
typedef float f32x4 __attribute__((ext_vector_type(4)));

constexpr int cB = 256, cN = 256, cF = 128, cO = 256;
constexpr int BN = cB * cN;
constexpr float D2_FLOOR = 1e-12f;
constexpr float EPS_F = 1.401298464324817e-45f;  // np.spacing(float32(0))

// ---------------- workspace byte offsets ----------------
// xc  : bf16 [BN][512]   (cols k*128+f; k=0..3)            64 MB
// W   : f32  [B][256][256] (affinity, dead after k_L)      64 MB  (x2T aliases first 16MB)
// x0T : bf16 [B][128][256]                                  16 MB
// x1T : bf16 [B][128][256]  (aliases xw bf16 [BN][128])     16 MB
// Lb  : bf16 [B][256][256]                                  32 MB
constexpr size_t OFF_XC  = 0;
constexpr size_t OFF_W   = OFF_XC + (size_t)BN * 512 * 2;
constexpr size_t OFF_X0T = OFF_W + (size_t)cB * cN * cN * 4;
constexpr size_t OFF_X1T = OFF_X0T + (size_t)cB * cF * cN * 2;
constexpr size_t OFF_LB  = OFF_X1T + (size_t)cB * cF * cN * 2;
constexpr size_t OFF_WT  = OFF_LB + (size_t)cB * cN * cN * 2;   // bf16 [256][512]
constexpr size_t OFF_MT  = OFF_WT + 512 * 256 * 2;              // bf16 [128][128]
constexpr size_t OFF_SQ  = OFF_MT + 128 * 128 * 2;              // f32 [BN]
constexpr size_t OFF_DI  = OFF_SQ + (size_t)BN * 4;             // f32 [BN]

// ---------------- async global->LDS (16B per lane) ----------------
__device__ __forceinline__ void gll16(const void* g, void* l) {
  __builtin_amdgcn_global_load_lds((const __attribute__((address_space(1))) void*)g,
                                   (__attribute__((address_space(3))) void*)l, 16, 0, 0);
}

// Stage nrf 16-row fragments x 2 k-slices (K-chunk of 64) from src (row stride ld
// elements) into frag-linear LDS: slot u=(rf*2+ks) holds 64 lanes x 16B, where lane l
// carries row rf*16+(l&15), cols k0+ks*32+8*(l>>4)..+7.  LDS dest is wave-uniform
// (global_load_lds writes base+lane*16), global src is per-lane pre-swizzled.
template<int NWAVE>
__device__ __forceinline__ void stage_panel(const bf16* __restrict__ src, int ld,
                                            int nrf, int k0, char* lds,
                                            int wid, int lane) {
  const bf16* g0 = src + (size_t)(lane & 15) * ld + k0 + 8 * (lane >> 4);
  const int nIss = nrf * 2;
  for (int u = wid; u < nIss; u += NWAVE) {
    int rf = u >> 1, ks = u & 1;
    gll16(g0 + (size_t)rf * 16 * ld + ks * 32, lds + (u << 10));
  }
}

// One K-chunk (64) of MFMA for a 128 x (NF*16) wave tile.
// A-frag (mf,ks) at Al+((mf*2+ks)<<10)+lane*16 ; B-frag at Bl+((nf*2+ks)<<10)+lane*16.
template<int NF>
__device__ __forceinline__ void mfma_chunk(const char* Al, const char* Bl, int lane,
                                           f32x4 acc[8][NF]) {
#pragma unroll
  for (int ks = 0; ks < 2; ++ks) {
    bf16x8 a[8];
#pragma unroll
    for (int mf = 0; mf < 8; ++mf)
      a[mf] = *(const bf16x8*)(Al + ((mf * 2 + ks) << 10) + lane * 16);
#pragma unroll
    for (int nf = 0; nf < NF; ++nf) {
      bf16x8 b = *(const bf16x8*)(Bl + ((nf * 2 + ks) << 10) + lane * 16);
#pragma unroll
      for (int mf = 0; mf < 8; ++mf)
        acc[mf][nf] = __builtin_amdgcn_mfma_f32_16x16x32_bf16(a[mf], b, acc[mf][nf], 0, 0, 0);
    }
  }
}

// ---------------- k_prep: mask+convert; write xc[:,0:128] and x0T ----------------
__global__ __launch_bounds__(256) void k_prep(const float* __restrict__ x,
                                              const int* __restrict__ na_p,
                                              bf16* __restrict__ xc,
                                              bf16* __restrict__ x0T) {
  __shared__ __align__(16) bf16 T[64][132];
  int b = blockIdx.x >> 2, i0 = (blockIdx.x & 3) * 64;
  int tid = threadIdx.x;
  int na = na_p[b];
#pragma unroll
  for (int it = 0; it < 8; ++it) {
    int ir = it * 8 + (tid >> 5);
    int f0 = (tid & 31) * 4;
    int i = i0 + ir;
    float m = (i < na) ? 1.f : 0.f;
    float4 v = *(const float4*)(x + ((size_t)b * cN + i) * cF + f0);
    bf16x4 pk = {(bf16)(v.x * m), (bf16)(v.y * m), (bf16)(v.z * m), (bf16)(v.w * m)};
    *(bf16x4*)(xc + ((size_t)b * cN + i) * 512 + f0) = pk;
    *(bf16x4*)(&T[ir][f0]) = pk;
  }
  __syncthreads();
  int f = tid >> 1, half = tid & 1;
  bf16* od = x0T + ((size_t)b * cF + f) * cN + i0 + half * 32;
#pragma unroll
  for (int c = 0; c < 32; c += 4) {
    int ii = half * 32 + c;
    bf16x4 pk = {T[ii][f], T[ii + 1][f], T[ii + 2][f], T[ii + 3][f]};
    *(bf16x4*)(od + c) = pk;
  }
}

// ---------------- k_wt: Wt[o][k*128+f]=weight[f*4+k][o]; MT[g][f]=M_L[f][g] ----------
__global__ __launch_bounds__(256) void k_wt(const float* __restrict__ wgt,
                                            const float* __restrict__ ML,
                                            bf16* __restrict__ Wt,
                                            bf16* __restrict__ MT) {
  int id = blockIdx.x * 256 + threadIdx.x;
  if (id < 512 * 256) {
    int o = id >> 9, d = id & 511;
    int k = d >> 7, f = d & 127;
    Wt[id] = (bf16)wgt[(f * 4 + k) * 256 + o];
  } else {
    int id2 = id - 512 * 256;
    if (id2 < 128 * 128) {
      int g = id2 >> 7, f = id2 & 127;
      MT[id2] = (bf16)ML[f * 128 + g];
    }
  }
}

// ---------------- k_xw_mfma: xw[n][g] = x0m @ M_L  (A=xc[:,0:128], Bt=MT) -----------
__global__ __launch_bounds__(256, 1) void k_xw_mfma(const bf16* __restrict__ xc,
                                                    const bf16* __restrict__ MT,
                                                    bf16* __restrict__ xw) {
  __shared__ __align__(16) char AL[2][16384];
  __shared__ __align__(16) char BL[2][16384];
  int tid = threadIdx.x, wid = tid >> 6, lane = tid & 63;
  int r0 = blockIdx.x * 128;
  const bf16* A = xc + (size_t)r0 * 512;
  f32x4 acc[8][2] = {};
  stage_panel<4>(A, 512, 8, 0, AL[0], wid, lane);
  stage_panel<4>(MT, 128, 8, 0, BL[0], wid, lane);
  __syncthreads();
#pragma unroll
  for (int kc = 0; kc < 2; ++kc) {
    if (kc < 1) {
      stage_panel<4>(A, 512, 8, 64, AL[1], wid, lane);
      stage_panel<4>(MT, 128, 8, 64, BL[1], wid, lane);
    }
    mfma_chunk<2>(AL[kc], BL[kc] + wid * 4096, lane, acc);
    __syncthreads();
  }
  int r4 = 4 * (lane >> 4), il = lane & 15;
#pragma unroll
  for (int mf = 0; mf < 8; ++mf)
#pragma unroll
    for (int nf = 0; nf < 2; ++nf)
#pragma unroll
      for (int r = 0; r < 4; ++r) {
        int row = r0 + mf * 16 + r4 + r;
        int g = wid * 32 + nf * 16 + il;
        xw[(size_t)row * cF + g] = (bf16)acc[mf][nf][r];
      }
}

// ---------------- k_sq: sq[row] = sum_f xw_bf16^2 (fp32) ----------------
__global__ __launch_bounds__(256) void k_sq(const bf16* __restrict__ xw,
                                            float* __restrict__ sq) {
  int tid = threadIdx.x, lane = tid & 63;
  int row = blockIdx.x * 4 + (tid >> 6);
  const bf16* p = xw + (size_t)row * cF + lane * 2;
  float a = (float)p[0], b2 = (float)p[1];
  float s = a * a + b2 * b2;
#pragma unroll
  for (int o = 32; o; o >>= 1) s += __shfl_down(s, o);
  if (lane == 0) sq[row] = s;
}

// ---------------- k_gram_mfma: W[i][j] = exp(-dist)*off  (shared xw panel) ----------
__global__ __launch_bounds__(512, 1) void k_gram_mfma(const bf16* __restrict__ xw,
                                                      const float* __restrict__ sq,
                                                      const int* __restrict__ na_p,
                                                      float* __restrict__ Wb) {
  __shared__ __align__(16) char P[2][32768];
  __shared__ float lsq[256];
  int b = blockIdx.x;
  int tid = threadIdx.x, wid = tid >> 6, lane = tid & 63;
  const bf16* X = xw + (size_t)b * cN * cF;
  int wm = wid >> 2, wn = wid & 3;
  f32x4 acc[8][4] = {};
  stage_panel<8>(X, cF, 16, 0, P[0], wid, lane);
  if (tid < 256) lsq[tid] = sq[b * cN + tid];
  __syncthreads();
#pragma unroll
  for (int kc = 0; kc < 2; ++kc) {
    if (kc < 1) stage_panel<8>(X, cF, 16, 64, P[1], wid, lane);
    mfma_chunk<4>(P[kc] + wm * 16384, P[kc] + wn * 8192, lane, acc);
    __syncthreads();
  }
  int na = na_p[b];
  int r4 = 4 * (lane >> 4), il = lane & 15;
  float* Wrow = Wb + (size_t)b * cN * cN;
#pragma unroll
  for (int mf = 0; mf < 8; ++mf)
#pragma unroll
    for (int nf = 0; nf < 4; ++nf) {
      int j = wn * 64 + nf * 16 + il;
      float sqj = lsq[j];
      bool mj = j < na;
#pragma unroll
      for (int r = 0; r < 4; ++r) {
        int i = wm * 128 + mf * 16 + r4 + r;
        float w = 0.f;
        if (mj && i < na && i != j) {
          float d2 = fmaxf(lsq[i] + sqj - 2.f * acc[mf][nf][r], D2_FLOOR);
          w = expf(-sqrtf(d2));
        }
        Wrow[(size_t)i * cN + j] = w;
      }
    }
}

// ---------------- k_dinv ----------------
__global__ __launch_bounds__(256) void k_dinv(const float* __restrict__ Wb,
                                              const int* __restrict__ na_p,
                                              float* __restrict__ dinv) {
  int tid = threadIdx.x, lane = tid & 63;
  int row = blockIdx.x * 4 + (tid >> 6);
  float4 v = *(const float4*)(Wb + (size_t)row * cN + lane * 4);
  float s = v.x + v.y + v.z + v.w;
#pragma unroll
  for (int o = 32; o; o >>= 1) s += __shfl_down(s, o);
  if (lane == 0) {
    int b = row >> 8, n = row & 255;
    dinv[row] = (n < na_p[b]) ? 1.f / sqrtf(s + EPS_F) : 0.f;
  }
}

// ---------------- k_L: llearn (fp32, to out) + L (bf16, for cheb) ----------------
__global__ __launch_bounds__(256) void k_L(const float* __restrict__ lap,
                                           const int* __restrict__ na_p,
                                           const float* __restrict__ dinv,
                                           const float* __restrict__ Wb,
                                           bf16* __restrict__ Lb,
                                           float* __restrict__ llearn) {
  size_t e = ((size_t)blockIdx.x * 256 + threadIdx.x) * 4;
  int j = (int)(e & 255);
  int i = (int)((e >> 8) & 255);
  int b = (int)(e >> 16);
  float4 w = *(const float4*)(Wb + e);
  float4 lp = *(const float4*)(lap + e);
  float di = dinv[b * cN + i];
  const float* djp = dinv + b * cN + j;
  int na = na_p[b];
  float mi = (i < na) ? 1.f : 0.f;
  float4 ll;
  bf16x4 lo;
#pragma unroll
  for (int c = 0; c < 4; ++c) {
    float v = -di * (&w.x)[c] * djp[c];
    if (i == j + c && i < na) v += 1.f;
    (&ll.x)[c] = v;
    float mj = (j + c < na) ? 1.f : 0.f;
    lo[c] = (bf16)(v + (&lp.x)[c] * mi * mj);
  }
  *(float4*)(llearn + e) = ll;
  *(bf16x4*)(Lb + e) = lo;
}

// ---------------- k_cheb_mfma: D[f][i] = (L @ x)^T ; out = alpha*D + beta*xpp ------
template<bool BETA, bool WRITE_T>
__global__ __launch_bounds__(256, 1) void k_cheb_mfma(const bf16* __restrict__ xT,
                                                      const bf16* __restrict__ Lb,
                                                      const bf16* __restrict__ xppT,
                                                      bf16* __restrict__ xoutT,
                                                      bf16* __restrict__ xc, int kcol) {
  __shared__ __align__(16) char AL[2][16384];
  __shared__ __align__(16) char BL[2][32768];
  int b = blockIdx.x;
  int tid = threadIdx.x, wid = tid >> 6, lane = tid & 63;
  const bf16* A = xT + (size_t)b * cF * cN;
  const bf16* Bm = Lb + (size_t)b * cN * cN;
  f32x4 acc[8][4] = {};
  stage_panel<4>(A, cN, 8, 0, AL[0], wid, lane);
  stage_panel<4>(Bm, cN, 16, 0, BL[0], wid, lane);
  __syncthreads();
#pragma unroll
  for (int kc = 0; kc < 4; ++kc) {
    int cur = kc & 1;
    if (kc < 3) {
      stage_panel<4>(A, cN, 8, (kc + 1) * 64, AL[cur ^ 1], wid, lane);
      stage_panel<4>(Bm, cN, 16, (kc + 1) * 64, BL[cur ^ 1], wid, lane);
    }
    mfma_chunk<4>(AL[cur], BL[cur] + wid * 8192, lane, acc);
    __syncthreads();
  }
  int i0 = wid * 64;
  int r4 = 4 * (lane >> 4), il = lane & 15;
#pragma unroll
  for (int mf = 0; mf < 8; ++mf)
#pragma unroll
    for (int nf = 0; nf < 4; ++nf) {
      int i = i0 + nf * 16 + il;
      int f0 = mf * 16 + r4;
      bf16x4 pk;
#pragma unroll
      for (int r = 0; r < 4; ++r) {
        float v = acc[mf][nf][r];
        if (BETA) v = 2.f * v - (float)xppT[(size_t)b * cF * cN + (size_t)(f0 + r) * cN + i];
        bf16 bv = (bf16)v;
        pk[r] = bv;
        if (WRITE_T) xoutT[(size_t)b * cF * cN + (size_t)(f0 + r) * cN + i] = bv;
      }
      *(bf16x4*)(xc + ((size_t)b * cN + i) * 512 + kcol + f0) = pk;
    }
}

// ---------------- k_out_mfma: out = relu((xc@Wt^T + bias)*mask) ----------------
__global__ __launch_bounds__(256, 1) void k_out_mfma(const bf16* __restrict__ xc,
                                                     const bf16* __restrict__ Wt,
                                                     const float* __restrict__ bias,
                                                     const int* __restrict__ na_p,
                                                     float* __restrict__ out) {
  __shared__ __align__(16) char AL[2][16384];
  __shared__ __align__(16) char BL[2][32768];
  int tid = threadIdx.x, wid = tid >> 6, lane = tid & 63;
  int r0 = blockIdx.x * 128;
  const bf16* A = xc + (size_t)r0 * 512;
  f32x4 acc[8][4] = {};
  stage_panel<4>(A, 512, 8, 0, AL[0], wid, lane);
  stage_panel<4>(Wt, 512, 16, 0, BL[0], wid, lane);
  __syncthreads();
  for (int kc = 0; kc < 8; ++kc) {
    int cur = kc & 1;
    if (kc < 7) {
      stage_panel<4>(A, 512, 8, (kc + 1) * 64, AL[cur ^ 1], wid, lane);
      stage_panel<4>(Wt, 512, 16, (kc + 1) * 64, BL[cur ^ 1], wid, lane);
    }
    mfma_chunk<4>(AL[cur], BL[cur] + wid * 8192, lane, acc);
    __syncthreads();
  }
  int na = na_p[r0 >> 8];
  int o0 = wid * 64;
  int r4 = 4 * (lane >> 4), il = lane & 15;
#pragma unroll
  for (int nf = 0; nf < 4; ++nf) {
    int o = o0 + nf * 16 + il;
    float bo = bias[o];
#pragma unroll
    for (int mf = 0; mf < 8; ++mf)
#pragma unroll
      for (int r = 0; r < 4; ++r) {
        int row = r0 + mf * 16 + r4 + r;
        float m = ((row & 255) < na) ? 1.f : 0.f;
        out[(size_t)row * cO + o] = fmaxf((acc[mf][nf][r] + bo) * m, 0.f);
      }
  }
}

// ---------------- launcher ----------------
extern "C" void kernel_launch(void* const* d_in, const int* in_sizes, int n_in,
                              void* d_out, int out_size, void* d_ws, size_t ws_size,
                              hipStream_t stream) {
  const float* x    = (const float*)d_in[0];
  const float* lap  = (const float*)d_in[1];
  const int*   na   = (const int*)d_in[2];
  const float* M_L  = (const float*)d_in[3];
  const float* wgt  = (const float*)d_in[4];
  const float* bias = (const float*)d_in[5];

  float* out    = (float*)d_out;
  float* llearn = out + (size_t)BN * cO;

  char* ws = (char*)d_ws;
  bf16*  xc  = (bf16*)(ws + OFF_XC);
  float* Wb  = (float*)(ws + OFF_W);
  bf16*  x2T = (bf16*)(ws + OFF_W);    // aliases W (dead after k_L)
  bf16*  x0T = (bf16*)(ws + OFF_X0T);
  bf16*  x1T = (bf16*)(ws + OFF_X1T);  // aliases xw (dead after k_gram)
  bf16*  xw  = (bf16*)(ws + OFF_X1T);
  bf16*  Lb  = (bf16*)(ws + OFF_LB);
  bf16*  Wt  = (bf16*)(ws + OFF_WT);
  bf16*  MT  = (bf16*)(ws + OFF_MT);
  float* sqb = (float*)(ws + OFF_SQ);
  float* dnv = (float*)(ws + OFF_DI);

  k_prep<<<dim3(1024), 256, 0, stream>>>(x, na, xc, x0T);
  k_wt<<<dim3(576), 256, 0, stream>>>(wgt, M_L, Wt, MT);
  k_xw_mfma<<<dim3(512), 256, 0, stream>>>(xc, MT, xw);
  k_sq<<<dim3(BN / 4), 256, 0, stream>>>(xw, sqb);
  k_gram_mfma<<<dim3(cB), 512, 0, stream>>>(xw, sqb, na, Wb);
  k_dinv<<<dim3(BN / 4), 256, 0, stream>>>(Wb, na, dnv);
  k_L<<<dim3(16384), 256, 0, stream>>>(lap, na, dnv, Wb, Lb, llearn);
  k_cheb_mfma<false, true><<<dim3(cB), 256, 0, stream>>>(x0T, Lb, x0T, x1T, xc, 128);
  k_cheb_mfma<true, true><<<dim3(cB), 256, 0, stream>>>(x1T, Lb, x0T, x2T, xc, 256);
  k_cheb_mfma<true, false><<<dim3(cB), 256, 0, stream>>>(x2T, Lb, x1T, x2T, xc, 384);
  k_out_mfma<<<dim3(512), 256, 0, stream>>>(xc, Wt, bias, na, out);
}